// Round 9
// baseline (488.130 us; speedup 1.0000x reference)
//
#include <hip/hip_runtime.h>
#include <hip/hip_bf16.h>
#include <cstddef>

// ---------------------------------------------------------------------------
// Constants for this problem: B=4, L=2048, D=1024
// ---------------------------------------------------------------------------
#define BB 4
#define LL 2048
#define DD 1024
#define MM (BB*LL)          // 8192 tokens
#define KF_STRIDE 2056      // complex elements per Kf row (>= 2049, 16B-aligned)

// LDS bank swizzle for float2 arrays: spreads Stockham write streams across
// bank-pairs. Modifies bits 2-3 only (stays in range).
#define SWZ(a) ((a) ^ (((a) >> 4) & 12))

typedef __bf16 bf16_t;
typedef __attribute__((ext_vector_type(8))) __bf16 bf16x8;
typedef __attribute__((ext_vector_type(4))) __bf16 bf16x4;
typedef __attribute__((ext_vector_type(4))) float f32x4;

// async global->LDS, 16 bytes per lane (global_load_lds_dwordx4)
#define GLD_LDS16(gp, lp) __builtin_amdgcn_global_load_lds(                 \
    (const __attribute__((address_space(1))) unsigned int*)(gp),            \
    (__attribute__((address_space(3))) unsigned int*)(lp), 16, 0, 0)

__device__ __forceinline__ float gelu_tanh(float x) {
    const float c = 0.7978845608028654f;   // sqrt(2/pi)
    float t = tanhf(c * (x + 0.044715f * x * x * x));
    return 0.5f * x * (1.0f + t);
}

__device__ __forceinline__ float2 cmul(float2 a, float2 b) {
    return make_float2(a.x * b.x - a.y * b.y, a.x * b.y + a.y * b.x);
}
__device__ __forceinline__ float2 cadd(float2 a, float2 b) {
    return make_float2(a.x + b.x, a.y + b.y);
}
__device__ __forceinline__ float2 csub(float2 a, float2 b) {
    return make_float2(a.x - b.x, a.y - b.y);
}
// multiply by i*sigma (sigma = +-1)
__device__ __forceinline__ float2 cmuli(float2 z, float s) {
    return make_float2(-s * z.y, s * z.x);
}

// ---------------------------------------------------------------------------
// fp32 -> bf16 cast of all 4 weight matrices in ONE launch.
// ---------------------------------------------------------------------------
__global__ __launch_bounds__(256) void cast_all_kernel(
    const float* __restrict__ s0, const float* __restrict__ s1,
    const float* __restrict__ s2, const float* __restrict__ s3,
    bf16_t* __restrict__ d0, bf16_t* __restrict__ d1,
    bf16_t* __restrict__ d2, bf16_t* __restrict__ d3)
{
    const int b = blockIdx.x;
    const float* s; bf16_t* d; int base;
    if (b < 3072)      { s = s0; d = d0; base = b; }
    else if (b < 4096) { s = s1; d = d1; base = b - 3072; }
    else if (b < 6144) { s = s2; d = d2; base = b - 4096; }
    else               { s = s3; d = d3; base = b - 6144; }
    const int i = (base * 256 + threadIdx.x) * 4;
    const float4 v = *(const float4*)(s + i);
    bf16x4 o;
    o[0] = (bf16_t)v.x; o[1] = (bf16_t)v.y; o[2] = (bf16_t)v.z; o[3] = (bf16_t)v.w;
    *(bf16x4*)(d + i) = o;
}

// ---------------------------------------------------------------------------
// RMSNorm -> bf16 output: one block per row of 1024 floats
// ---------------------------------------------------------------------------
__global__ __launch_bounds__(256) void rmsnorm_bf16_kernel(
    const float* __restrict__ in, const float* __restrict__ w,
    bf16_t* __restrict__ out)
{
    const int row = blockIdx.x;
    const float4* ip = (const float4*)(in + (size_t)row * DD);
    float4 v = ip[threadIdx.x];
    float ss = v.x*v.x + v.y*v.y + v.z*v.z + v.w*v.w;
    #pragma unroll
    for (int off = 32; off > 0; off >>= 1) ss += __shfl_down(ss, off, 64);
    __shared__ float sums[4];
    const int wid = threadIdx.x >> 6;
    if ((threadIdx.x & 63) == 0) sums[wid] = ss;
    __syncthreads();
    const float tot = sums[0] + sums[1] + sums[2] + sums[3];
    const float scale = rsqrtf(tot * (1.0f / (float)DD) + 1e-8f);
    const float4 wv = ((const float4*)w)[threadIdx.x];
    bf16x4 o;
    o[0] = (bf16_t)(v.x * scale * wv.x);
    o[1] = (bf16_t)(v.y * scale * wv.y);
    o[2] = (bf16_t)(v.z * scale * wv.z);
    o[3] = (bf16_t)(v.w * scale * wv.w);
    *(bf16x4*)(out + (size_t)row * DD + threadIdx.x * 4) = o;
}

// ---------------------------------------------------------------------------
// bf16 MFMA GEMM, 512-thread variant (R7/R8-VERIFIED, best for K=1024):
// 128x128 tile, BK=64, 8 waves (2x4), per-wave 64x32, acc 4x2. VGPR 52 ->
// 4 waves/SIMD (occupancy 39%, MfmaUtil 32% measured). Double-buffered
// 2-phase schedule: issue next-tile global_load_lds into buf^1 first,
// compute cur tile, ONE __syncthreads() per K-tile. setprio(1) around MFMA.
// Used for steps 3/7/9. Step 10 (K=2048: 2x barriers x 8-wave rendezvous
// regressed to 76.5us here) uses the 256-thr kernel below.
// EPI: 0 = bias, 1 = bias + residual, 2 = bias + tanh-GELU
// BIASROW: bias indexed by output row (for transposed-output GEMMs)
// ---------------------------------------------------------------------------
template<int EPI, bool BF16OUT, bool BIASROW = false>
__global__ __launch_bounds__(512) void gemm_mfma_k512(
    const bf16_t* __restrict__ A,    // (M,K)
    const bf16_t* __restrict__ W,    // (N,K)
    const float* __restrict__ bias,  // (N) or (M) if BIASROW
    const float* __restrict__ res,   // (M,N) or nullptr
    float* __restrict__ Cf,          // fp32 out (if !BF16OUT)
    bf16_t* __restrict__ Cb,         // bf16 out (if BF16OUT)
    int M, int N, int K)
{
    __shared__ __align__(16) bf16_t As[2][128 * 64];   // 32 KB
    __shared__ __align__(16) bf16_t Ws[2][128 * 64];   // 32 KB
    const int tid  = threadIdx.x;                      // 0..511
    const int bm   = blockIdx.y * 128;
    const int bn   = blockIdx.x * 128;
    const int lane = tid & 63;
    const int wave = tid >> 6;                         // 0..7
    const int wr   = (wave >> 2) * 64;                 // row-group: 0 / 64
    const int wc   = (wave & 3) * 32;                  // col-group: 0/32/64/96

    int srow[2], sqg[2];
    #pragma unroll
    for (int c = 0; c < 2; ++c) {
        const int p = c * 512 + tid;
        srow[c] = p >> 3;
        sqg[c]  = (((p & 7) ^ (srow[c] & 7)) << 3);
    }

    f32x4 acc[4][2] = {};

    const int fr = lane & 15;
    const int fc = (lane >> 4) * 8;

    const int nt = K >> 6;

    #pragma unroll
    for (int c = 0; c < 2; ++c) {
        GLD_LDS16(A + (size_t)(bm + srow[c]) * K + sqg[c],
                  &As[0][c * 4096 + tid * 8]);
        GLD_LDS16(W + (size_t)(bn + srow[c]) * K + sqg[c],
                  &Ws[0][c * 4096 + tid * 8]);
    }
    __syncthreads();

    int cur = 0;
    for (int t = 0; t < nt; ++t) {
        if (t + 1 < nt) {
            const int k0 = (t + 1) << 6;
            #pragma unroll
            for (int c = 0; c < 2; ++c) {
                GLD_LDS16(A + (size_t)(bm + srow[c]) * K + k0 + sqg[c],
                          &As[cur ^ 1][c * 4096 + tid * 8]);
                GLD_LDS16(W + (size_t)(bn + srow[c]) * K + k0 + sqg[c],
                          &Ws[cur ^ 1][c * 4096 + tid * 8]);
            }
        }
        #pragma unroll
        for (int ks = 0; ks < 64; ks += 32) {
            const int q = (ks + fc) >> 3;
            bf16x8 af[4], wf[2];
            #pragma unroll
            for (int i = 0; i < 4; ++i) {
                const int r = wr + i*16 + fr;
                af[i] = *(const bf16x8*)(&As[cur][r * 64 + ((q ^ (r & 7)) << 3)]);
            }
            #pragma unroll
            for (int j = 0; j < 2; ++j) {
                const int r = wc + j*16 + fr;
                wf[j] = *(const bf16x8*)(&Ws[cur][r * 64 + ((q ^ (r & 7)) << 3)]);
            }
            __builtin_amdgcn_s_setprio(1);
            #pragma unroll
            for (int i = 0; i < 4; ++i)
                #pragma unroll
                for (int j = 0; j < 2; ++j)
                    acc[i][j] = __builtin_amdgcn_mfma_f32_16x16x32_bf16(
                        af[i], wf[j], acc[i][j], 0, 0, 0);
            __builtin_amdgcn_s_setprio(0);
        }
        __syncthreads();
        cur ^= 1;
    }

    const int fq = lane >> 4;
    #pragma unroll
    for (int i = 0; i < 4; ++i) {
        const int row0 = bm + wr + i*16 + fq*4;
        #pragma unroll
        for (int j = 0; j < 2; ++j) {
            const int col = bn + wc + j*16 + fr;
            const float bcol = BIASROW ? 0.0f : bias[col];
            #pragma unroll
            for (int r = 0; r < 4; ++r) {
                float v = acc[i][j][r] + (BIASROW ? bias[row0 + r] : bcol);
                if constexpr (EPI == 2) v = gelu_tanh(v);
                if constexpr (EPI == 1) v += res[(size_t)(row0 + r) * N + col];
                if constexpr (BF16OUT)
                    Cb[(size_t)(row0 + r) * N + col] = (bf16_t)v;
                else
                    Cf[(size_t)(row0 + r) * N + col] = v;
            }
        }
    }
}

// ---------------------------------------------------------------------------
// bf16 MFMA GEMM, 256-thread variant (R2-VERIFIED): 4 waves (2x2), per-wave
// 64x64, acc 4x4. Fewer waves per barrier rendezvous -> best for K=2048
// (step 10), where the 512-thr variant's doubled barrier weight regressed.
// ---------------------------------------------------------------------------
template<int EPI, bool BF16OUT, bool BIASROW = false>
__global__ __launch_bounds__(256) void gemm_mfma_k256(
    const bf16_t* __restrict__ A,    // (M,K)
    const bf16_t* __restrict__ W,    // (N,K)
    const float* __restrict__ bias,  // (N) or (M) if BIASROW
    const float* __restrict__ res,   // (M,N) or nullptr
    float* __restrict__ Cf,          // fp32 out (if !BF16OUT)
    bf16_t* __restrict__ Cb,         // bf16 out (if BF16OUT)
    int M, int N, int K)
{
    __shared__ __align__(16) bf16_t As[2][128 * 64];   // 32 KB
    __shared__ __align__(16) bf16_t Ws[2][128 * 64];   // 32 KB
    const int tid  = threadIdx.x;
    const int bm   = blockIdx.y * 128;
    const int bn   = blockIdx.x * 128;
    const int lane = tid & 63;
    const int wave = tid >> 6;
    const int wr   = (wave >> 1) * 64;
    const int wc   = (wave & 1) * 64;

    int srow[4], sqg[4];
    #pragma unroll
    for (int c = 0; c < 4; ++c) {
        const int p = c * 256 + tid;
        srow[c] = p >> 3;
        sqg[c]  = (((p & 7) ^ (srow[c] & 7)) << 3);
    }

    f32x4 acc[4][4] = {};

    const int fr = lane & 15;
    const int fc = (lane >> 4) * 8;

    const int nt = K >> 6;

    #pragma unroll
    for (int c = 0; c < 4; ++c) {
        GLD_LDS16(A + (size_t)(bm + srow[c]) * K + sqg[c],
                  &As[0][c * 2048 + tid * 8]);
        GLD_LDS16(W + (size_t)(bn + srow[c]) * K + sqg[c],
                  &Ws[0][c * 2048 + tid * 8]);
    }
    __syncthreads();

    int cur = 0;
    for (int t = 0; t < nt; ++t) {
        if (t + 1 < nt) {
            const int k0 = (t + 1) << 6;
            #pragma unroll
            for (int c = 0; c < 4; ++c) {
                GLD_LDS16(A + (size_t)(bm + srow[c]) * K + k0 + sqg[c],
                          &As[cur ^ 1][c * 2048 + tid * 8]);
                GLD_LDS16(W + (size_t)(bn + srow[c]) * K + k0 + sqg[c],
                          &Ws[cur ^ 1][c * 2048 + tid * 8]);
            }
        }
        #pragma unroll
        for (int ks = 0; ks < 64; ks += 32) {
            const int q = (ks + fc) >> 3;
            bf16x8 af[4], wf[4];
            #pragma unroll
            for (int i = 0; i < 4; ++i) {
                const int r = wr + i*16 + fr;
                af[i] = *(const bf16x8*)(&As[cur][r * 64 + ((q ^ (r & 7)) << 3)]);
            }
            #pragma unroll
            for (int j = 0; j < 4; ++j) {
                const int r = wc + j*16 + fr;
                wf[j] = *(const bf16x8*)(&Ws[cur][r * 64 + ((q ^ (r & 7)) << 3)]);
            }
            __builtin_amdgcn_s_setprio(1);
            #pragma unroll
            for (int i = 0; i < 4; ++i)
                #pragma unroll
                for (int j = 0; j < 4; ++j)
                    acc[i][j] = __builtin_amdgcn_mfma_f32_16x16x32_bf16(
                        af[i], wf[j], acc[i][j], 0, 0, 0);
            __builtin_amdgcn_s_setprio(0);
        }
        __syncthreads();
        cur ^= 1;
    }

    const int fq = lane >> 4;
    #pragma unroll
    for (int i = 0; i < 4; ++i) {
        const int row0 = bm + wr + i*16 + fq*4;
        #pragma unroll
        for (int j = 0; j < 4; ++j) {
            const int col = bn + wc + j*16 + fr;
            const float bcol = BIASROW ? 0.0f : bias[col];
            #pragma unroll
            for (int r = 0; r < 4; ++r) {
                float v = acc[i][j][r] + (BIASROW ? bias[row0 + r] : bcol);
                if constexpr (EPI == 2) v = gelu_tanh(v);
                if constexpr (EPI == 1) v += res[(size_t)(row0 + r) * N + col];
                if constexpr (BF16OUT)
                    Cb[(size_t)(row0 + r) * N + col] = (bf16_t)v;
                else
                    Cf[(size_t)(row0 + r) * N + col] = v;
            }
        }
    }
}

// ---------------------------------------------------------------------------
// Depthwise causal k=3 short filter on u_t (3D, M) channel-major bf16.
// Vectorized bf16x8 loads (16 B/lane), 8 positions per thread, 16-B stores.
// ---------------------------------------------------------------------------
__global__ __launch_bounds__(256) void shortfilter_kernel(
    const bf16_t* __restrict__ ut, const float* __restrict__ sw,
    const float* __restrict__ sb, bf16_t* __restrict__ x0t,
    float* __restrict__ vin)
{
    const int d = blockIdx.x;             // 0..1023
    const int c0 = d, c1 = DD + d, c2 = 2 * DD + d;
    const float w0a = sw[c0*3+0], w0b = sw[c0*3+1], w0c = sw[c0*3+2], b0 = sb[c0];
    const float w1a = sw[c1*3+0], w1b = sw[c1*3+1], w1c = sw[c1*3+2], b1 = sb[c1];
    const float w2a = sw[c2*3+0], w2b = sw[c2*3+1], w2c = sw[c2*3+2], b2 = sb[c2];
    const bf16_t* r0 = ut + (size_t)c0 * MM;
    const bf16_t* r1 = ut + (size_t)c1 * MM;
    const bf16_t* r2 = ut + (size_t)c2 * MM;
    bf16_t* o0 = x0t + (size_t)d * MM;
    float*  o1 = vin + (size_t)d * MM;
    for (int m0 = threadIdx.x * 8; m0 < MM; m0 += 2048) {
        const int l0 = m0 & (LL - 1);
        const bf16x8 a0 = *(const bf16x8*)(r0 + m0);
        const bf16x8 a1 = *(const bf16x8*)(r1 + m0);
        const bf16x8 a2 = *(const bf16x8*)(r2 + m0);
        float u0[10], u1[10], u2[10];
        u0[0] = u0[1] = u1[0] = u1[1] = u2[0] = u2[1] = 0.0f;
        if (l0 != 0) {
            u0[0] = (float)r0[m0-2]; u0[1] = (float)r0[m0-1];
            u1[0] = (float)r1[m0-2]; u1[1] = (float)r1[m0-1];
            u2[0] = (float)r2[m0-2]; u2[1] = (float)r2[m0-1];
        }
        #pragma unroll
        for (int i = 0; i < 8; ++i) {
            u0[i+2] = (float)a0[i];
            u1[i+2] = (float)a1[i];
            u2[i+2] = (float)a2[i];
        }
        bf16x8 ov;
        float v1o[8];
        #pragma unroll
        for (int i = 0; i < 8; ++i) {
            const float v0 = w0c*u0[i+2] + w0b*u0[i+1] + w0a*u0[i] + b0;
            const float v1 = w1c*u1[i+2] + w1b*u1[i+1] + w1a*u1[i] + b1;
            const float v2 = w2c*u2[i+2] + w2b*u2[i+1] + w2a*u2[i] + b2;
            ov[i] = (bf16_t)v0;
            v1o[i] = v2 * v1;
        }
        *(bf16x8*)(o0 + m0) = ov;
        *(float4*)(o1 + m0)     = make_float4(v1o[0], v1o[1], v1o[2], v1o[3]);
        *(float4*)(o1 + m0 + 4) = make_float4(v1o[4], v1o[5], v1o[6], v1o[7]);
    }
}

// ---------------------------------------------------------------------------
// Implicit filter MLP, phase 1: h2t (64, L).
// Block = 32 l-positions x 64 j, grid = 64 blocks.
// ---------------------------------------------------------------------------
__global__ __launch_bounds__(256) void filtermlp_kernel(
    const float* __restrict__ w1, const float* __restrict__ b1,
    const float* __restrict__ f1, const float* __restrict__ w2,
    const float* __restrict__ b2, const float* __restrict__ f2,
    float* __restrict__ h2t)
{
    __shared__ float w2s[64 * 64];      // 16 KB
    __shared__ float h1s[64][32];       // 8 KB, [j][l]
    const int tid = threadIdx.x;
    #pragma unroll
    for (int i = 0; i < 4; ++i)
        ((float4*)w2s)[tid + 256 * i] = ((const float4*)w2)[tid + 256 * i];

    const int l0 = blockIdx.x * 32;
    const int l  = tid & 31;
    const float fl = (float)(l0 + l);
    const float t   = fl * (1.0f / (float)(LL - 1));
    const float ang = 1e-4f * 6.283185307179586f * fl * (1.0f / (float)LL);
    const float z0 = t, z1 = cosf(ang), z2 = -sinf(ang);

    #pragma unroll
    for (int i = 0; i < 8; ++i) {
        const int j = (tid >> 5) + 8 * i;
        const float s = w1[j*3+0]*z0 + w1[j*3+1]*z1 + w1[j*3+2]*z2 + b1[j];
        h1s[j][l] = sinf(f1[j] * s);
    }
    __syncthreads();

    const int jb = (tid >> 5) * 8;
    float acc[8];
    #pragma unroll
    for (int i = 0; i < 8; ++i) acc[i] = b2[jb + i];
    #pragma unroll
    for (int jj = 0; jj < 64; jj += 4) {
        const float h0 = h1s[jj + 0][l];
        const float h1v = h1s[jj + 1][l];
        const float h2v = h1s[jj + 2][l];
        const float h3 = h1s[jj + 3][l];
        #pragma unroll
        for (int i = 0; i < 8; ++i) {
            const float4 wv = *(const float4*)&w2s[(jb + i) * 64 + jj];
            acc[i] += wv.x * h0 + wv.y * h1v + wv.z * h2v + wv.w * h3;
        }
    }
    #pragma unroll
    for (int i = 0; i < 8; ++i)
        h2t[(size_t)(jb + i) * LL + l0 + l] = sinf(f2[jb + i] * acc[i]);
}

// ---------------------------------------------------------------------------
// Implicit filter, phase 2: kfilt[d][l] = (w3[d,:] . h2t[:,l]) * exp(-t|delta_d|)
// ---------------------------------------------------------------------------
__global__ __launch_bounds__(256) void filtermod_kernel(
    const float* __restrict__ w3, const float* __restrict__ h2t,
    float* __restrict__ kfilt)
{
    __shared__ float w3s[32 * 64];      // 8 KB
    const int d0 = blockIdx.y * 32;
    const int l  = blockIdx.x * 256 + threadIdx.x;
    for (int i = threadIdx.x; i < 32 * 64; i += 256) w3s[i] = w3[d0 * 64 + i];
    __syncthreads();
    float acc[32] = {};
    for (int j = 0; j < 64; ++j) {
        const float v = h2t[j * LL + l];
        #pragma unroll
        for (int dd = 0; dd < 32; ++dd) acc[dd] += w3s[dd*64 + j] * v;
    }
    const float t = (float)l / (float)(LL - 1);
    const float min_decay = -3.0701134573253944f;   // ln(1e-2)/1.5
    const float max_decay = -15.350567286626972f;   // ln(1e-2)/0.3
    #pragma unroll
    for (int dd = 0; dd < 32; ++dd) {
        const int d = d0 + dd;
        const float delta = fabsf(min_decay + (max_decay - min_decay) * (float)d / (float)(DD - 1));
        kfilt[(size_t)d * LL + l] = acc[dd] * expf(-t * delta);
    }
}

// ---------------------------------------------------------------------------
// 4096-point complex Stockham RADIX-8 FFT, in-place in 32 KB LDS.
// 4 stages (4096 = 8^4), 512 threads, one 8-point butterfly per thread per
// stage (read-all / barrier / write-all: race-free).
// R17: twiddle-table version REVERTED (R8: per-stage table gathers cost
// ~5-10us vs pipelined __sincosf -- L1-missing 7x64-entry gathers/wave).
// SIGN = -1 forward, +1 unnormalized inverse. Ends with __syncthreads().
// ---------------------------------------------------------------------------
template<int SIGN>
__device__ __forceinline__ void fft4096_r8_ip(float2* __restrict__ buf)
{
    const float fs = (float)SIGN;
    const float RH = 0.7071067811865476f;   // sqrt(2)/2
    const int tid = threadIdx.x;            // 0..511
    #pragma unroll
    for (int t = 0; t < 4; ++t) {
        const int ls = 3 * t;               // log2(stride): 0,3,6,9
        const int s  = 1 << ls;
        const float theta = fs * 6.283185307179586f / (float)(4096 >> ls);
        float2 a[8];
        #pragma unroll
        for (int m = 0; m < 8; ++m) a[m] = buf[SWZ(tid + m * 512)];
        __syncthreads();
        const int p = tid >> ls;
        const int q = tid & (s - 1);
        float sn, cs;
        __sincosf(theta * (float)p, &sn, &cs);
        const float2 W1 = make_float2(cs, sn);
        const float2 W2 = cmul(W1, W1);
        const float2 W3 = cmul(W2, W1);
        const float2 W4 = cmul(W2, W2);
        const float2 W5 = cmul(W4, W1);
        const float2 W6 = cmul(W4, W2);
        const float2 W7 = cmul(W4, W3);
        // DFT4 of evens (a0,a2,a4,a6) and odds (a1,a3,a5,a7)
        const float2 es = cadd(a[0], a[4]), ed = csub(a[0], a[4]);
        const float2 fs2 = cadd(a[2], a[6]), fd = csub(a[2], a[6]);
        const float2 E0 = cadd(es, fs2);
        const float2 E1 = cadd(ed, cmuli(fd, fs));
        const float2 E2 = csub(es, fs2);
        const float2 E3 = csub(ed, cmuli(fd, fs));
        const float2 os = cadd(a[1], a[5]), od = csub(a[1], a[5]);
        const float2 gs = cadd(a[3], a[7]), gd = csub(a[3], a[7]);
        const float2 O0 = cadd(os, gs);
        const float2 O1 = cadd(od, cmuli(gd, fs));
        const float2 O2 = csub(os, gs);
        const float2 O3 = csub(od, cmuli(gd, fs));
        // T_m = w8^m * O_m  (w8 = e^{i*sign*pi/4})
        const float2 T0 = O0;
        const float2 T1 = make_float2(RH * (O1.x - fs * O1.y), RH * (fs * O1.x + O1.y));
        const float2 T2 = cmuli(O2, fs);
        const float2 T3 = make_float2(RH * (-O3.x - fs * O3.y), RH * (fs * O3.x - O3.y));
        const int o = q + (p << (ls + 3));
        buf[SWZ(o)]         = cadd(E0, T0);
        buf[SWZ(o + s)]     = cmul(W1, cadd(E1, T1));
        buf[SWZ(o + 2*s)]   = cmul(W2, cadd(E2, T2));
        buf[SWZ(o + 3*s)]   = cmul(W3, cadd(E3, T3));
        buf[SWZ(o + 4*s)]   = cmul(W4, csub(E0, T0));
        buf[SWZ(o + 5*s)]   = cmul(W5, csub(E1, T1));
        buf[SWZ(o + 6*s)]   = cmul(W6, csub(E2, T2));
        buf[SWZ(o + 7*s)]   = cmul(W7, csub(E3, T3));
        __syncthreads();
    }
}

// ---------------------------------------------------------------------------
// FFT of filter rows, two real rows per block (z = k_{2d} + i*k_{2d+1}).
// ---------------------------------------------------------------------------
__global__ __launch_bounds__(512, 4) void kfft_kernel(
    const float* __restrict__ kfilt, float2* __restrict__ Kf)
{
    __shared__ float2 fb[4096];           // 32 KB
    const int d0 = blockIdx.x * 2;
    const float* k0 = kfilt + (size_t)d0 * LL;
    const float* k1 = k0 + LL;
    const float inv = 1.0f / 4096.0f;
    const int tid = threadIdx.x;
    for (int i = tid; i < 2048; i += 512) {
        fb[SWZ(i)]        = make_float2(k0[i] * inv, k1[i] * inv);
        fb[SWZ(i + 2048)] = make_float2(0.f, 0.f);
    }
    __syncthreads();
    fft4096_r8_ip<-1>(fb);
    float2* o0 = Kf + (size_t)d0 * KF_STRIDE;
    float2* o1 = o0 + KF_STRIDE;
    for (int k = tid; k <= 2048; k += 512) {
        const float2 z1 = fb[SWZ(k)];
        const float2 z2 = fb[SWZ((4096 - k) & 4095)];
        o0[k] = make_float2(0.5f * (z1.x + z2.x), 0.5f * (z1.y - z2.y));
        o1[k] = make_float2(0.5f * (z1.y + z2.y), 0.5f * (z2.x - z1.x));
    }
}

// ---------------------------------------------------------------------------
// Long conv, two real rows per block: z = v1 + i*v2, filter k is REAL.
// ---------------------------------------------------------------------------
__global__ __launch_bounds__(512, 4) void fftconv_kernel(
    float* __restrict__ vio, const float2* __restrict__ Kf,
    const float* __restrict__ fbias)
{
    __shared__ float2 fb[4096];           // 32 KB
    const int blk = blockIdx.x;          // [0, 2048)
    const int d   = blk >> 1;
    float* v1 = vio + (size_t)(2 * blk) * LL;
    float* v2 = v1 + LL;
    const int tid = threadIdx.x;
    for (int i = tid; i < 2048; i += 512) {
        fb[SWZ(i)]        = make_float2(v1[i], v2[i]);
        fb[SWZ(i + 2048)] = make_float2(0.f, 0.f);
    }
    __syncthreads();
    fft4096_r8_ip<-1>(fb);
    const float2* kf = Kf + (size_t)d * KF_STRIDE;
    for (int i = tid; i < 4096; i += 512) {
        float2 k;
        if (i <= 2048) k = kf[i];
        else { const float2 t = kf[4096 - i]; k = make_float2(t.x, -t.y); }
        fb[SWZ(i)] = cmul(fb[SWZ(i)], k);
    }
    __syncthreads();
    fft4096_r8_ip<1>(fb);
    const float bias = fbias[d];
    for (int i = tid; i < 2048; i += 512) {
        const float2 zy = fb[SWZ(i)];
        v1[i] = zy.x + bias * v1[i];
        v2[i] = zy.y + bias * v2[i];
    }
}

// ---------------------------------------------------------------------------
// gated_bf16(B,L,D) = bf16( y(D,B,L) * x0t(D,B,L) )  -- LDS 32x32 transpose
// ---------------------------------------------------------------------------
__global__ __launch_bounds__(256) void gate_transpose_kernel(
    const float* __restrict__ y, const bf16_t* __restrict__ x0t,
    bf16_t* __restrict__ g)
{
    __shared__ float tile[32][33];
    const int b  = blockIdx.z;
    const int l0 = blockIdx.x * 32;
    const int d0 = blockIdx.y * 32;
    const int tx  = threadIdx.x & 31;
    const int tyb = threadIdx.x >> 5;    // 0..7
    #pragma unroll
    for (int i = 0; i < 4; ++i) {
        const int dy = tyb + i * 8;
        const size_t src = ((size_t)(d0 + dy) * BB + b) * LL + l0 + tx;
        tile[dy][tx] = y[src] * (float)x0t[src];
    }
    __syncthreads();
    #pragma unroll
    for (int i = 0; i < 4; ++i) {
        const int ly = tyb + i * 8;
        g[((size_t)(b * LL + l0 + ly)) * DD + d0 + tx] = (bf16_t)tile[tx][ly];
    }
}

// ---------------------------------------------------------------------------
// Launch
// ---------------------------------------------------------------------------
extern "C" void kernel_launch(void* const* d_in, const int* in_sizes, int n_in,
                              void* d_out, int out_size, void* d_ws, size_t ws_size,
                              hipStream_t stream)
{
    (void)in_sizes; (void)n_in; (void)out_size; (void)ws_size;
    const float* x   = (const float*)d_in[0];
    const float* nw0 = (const float*)d_in[1];
    const float* ipw = (const float*)d_in[2];
    const float* ipb = (const float*)d_in[3];
    const float* sfw = (const float*)d_in[4];
    const float* sfb = (const float*)d_in[5];
    const float* w1  = (const float*)d_in[6];
    const float* b1  = (const float*)d_in[7];
    const float* f1  = (const float*)d_in[8];
    const float* w2  = (const float*)d_in[9];
    const float* b2  = (const float*)d_in[10];
    const float* f2  = (const float*)d_in[11];
    const float* w3  = (const float*)d_in[12];
    const float* fbv = (const float*)d_in[13];
    const float* opw = (const float*)d_in[14];
    const float* opb = (const float*)d_in[15];
    const float* nw1 = (const float*)d_in[16];
    const float* fw1 = (const float*)d_in[17];
    const float* fb1 = (const float*)d_in[18];
    const float* fw2 = (const float*)d_in[19];
    const float* fb2 = (const float*)d_in[20];
    float* out = (float*)d_out;

    float* ws = (float*)d_ws;
    bf16_t* utb    = (bf16_t*)ws;
    bf16_t* gatedb = (bf16_t*)ws;                       // 8,388,608 bf16
    float*  h      = ws + 4194304;                      // 8,388,608 f
    bf16_t* midb   = (bf16_t*)(ws + 12582912);          // 16,777,216 bf16
    bf16_t* xnb    = (bf16_t*)(ws + 25165824);          // 8M bf16 (also hn later)
    bf16_t* x0tb   = (bf16_t*)(ws + 29360128);          // 8,388,608 bf16 (D,B,L)
    float*  vio    = ws + 37748736;                     // 8,388,608 f (D,B,L)
    float*  kfilt  = ws + 46137344;                     // 2,097,152 f
    float2* Kf     = (float2*)(ws + 48234496);          // 1024 x KF_STRIDE cplx
    bf16_t* ipwb   = (bf16_t*)(ws + 52445184);          // 3,145,728 bf16
    bf16_t* opwb   = ipwb + 3145728;                    // 1,048,576 bf16
    bf16_t* fw1b   = opwb + 1048576;                    // 2,097,152 bf16
    bf16_t* fw2b   = fw1b + 2097152;                    // 2,097,152 bf16
    float*  h2t    = ws + 56639488;                     // (64, L) = 131,072 f

    // 0. weight casts (single launch, region-dispatched)
    cast_all_kernel<<<8192, 256, 0, stream>>>(ipw, opw, fw1, fw2,
                                              ipwb, opwb, fw1b, fw2b);
    // 1. implicit filter: MLP phase (h2t), modulation phase (kfilt), FFT (Kf)
    filtermlp_kernel<<<LL/32, 256, 0, stream>>>(w1, b1, f1, w2, b2, f2, h2t);
    filtermod_kernel<<<dim3(LL/256, DD/32), 256, 0, stream>>>(w3, h2t, kfilt);
    kfft_kernel<<<DD/2, 512, 0, stream>>>(kfilt, Kf);
    // 2. xn = bf16(rmsnorm(x, norm_in_w))
    rmsnorm_bf16_kernel<<<MM, 256, 0, stream>>>(x, nw0, xnb);
    // 3. u_t = in_proj_w @ xn^T + b (transposed output, bf16) -- 512 thr
    gemm_mfma_k512<0, true, true><<<dim3(MM/128, 3072/128), 512, 0, stream>>>(
        ipwb, xnb, ipb, nullptr, nullptr, utb, 3*DD, MM, DD);
    // 4. short filter -> x0t (D,B,L) bf16, vin (D,B,L) fp32
    shortfilter_kernel<<<DD, 256, 0, stream>>>(utb, sfw, sfb, x0tb, vio);
    // 5. vio <- causal_conv(vio, k) + filter_bias * vio   (2 rows per block)
    fftconv_kernel<<<BB*DD/2, 512, 0, stream>>>(vio, Kf, fbv);
    // 6. gated_bf16(B,L,D) = y * x0
    gate_transpose_kernel<<<dim3(LL/32, DD/32, BB), 256, 0, stream>>>(vio, x0tb, gatedb);
    // 7. h = gated @ out_proj_w^T + b + x   (M=8192, N=1024, K=1024) -- 512 thr
    gemm_mfma_k512<1, false><<<dim3(DD/128, MM/128), 512, 0, stream>>>(
        gatedb, opwb, opb, x, h, nullptr, MM, DD, DD);
    // 8. hn = bf16(rmsnorm(h, norm_w))
    rmsnorm_bf16_kernel<<<MM, 256, 0, stream>>>(h, nw1, xnb);
    // 9. mid = bf16(gelu(hn @ ffn_w1^T + b))  (M=8192, N=2048, K=1024) -- 512 thr
    gemm_mfma_k512<2, true><<<dim3(2*DD/128, MM/128), 512, 0, stream>>>(
        xnb, fw1b, fb1, nullptr, nullptr, midb, MM, 2*DD, DD);
    // 10. out = mid @ ffn_w2^T + b + h      (M=8192, N=1024, K=2048) -- 256 thr
    gemm_mfma_k256<1, false><<<dim3(DD/128, MM/128), 256, 0, stream>>>(
        midb, fw2b, fb2, h, out, nullptr, MM, DD, 2*DD);
}

// Round 10
// 474.190 us; speedup vs baseline: 1.0294x; 1.0294x over previous
//
#include <hip/hip_runtime.h>
#include <hip/hip_bf16.h>
#include <cstddef>

// ---------------------------------------------------------------------------
// Constants for this problem: B=4, L=2048, D=1024
// ---------------------------------------------------------------------------
#define BB 4
#define LL 2048
#define DD 1024
#define MM (BB*LL)          // 8192 tokens
#define KF_STRIDE 2056      // complex elements per Kf row (>= 2049, 16B-aligned)

// LDS bank swizzle for float2 arrays: spreads Stockham write streams across
// bank-pairs. Modifies bits 2-3 only (stays in range).
#define SWZ(a) ((a) ^ (((a) >> 4) & 12))

typedef __bf16 bf16_t;
typedef __attribute__((ext_vector_type(8))) __bf16 bf16x8;
typedef __attribute__((ext_vector_type(4))) __bf16 bf16x4;
typedef __attribute__((ext_vector_type(4))) float f32x4;

// async global->LDS, 16 bytes per lane (global_load_lds_dwordx4)
#define GLD_LDS16(gp, lp) __builtin_amdgcn_global_load_lds(                 \
    (const __attribute__((address_space(1))) unsigned int*)(gp),            \
    (__attribute__((address_space(3))) unsigned int*)(lp), 16, 0, 0)

__device__ __forceinline__ float gelu_tanh(float x) {
    const float c = 0.7978845608028654f;   // sqrt(2/pi)
    float t = tanhf(c * (x + 0.044715f * x * x * x));
    return 0.5f * x * (1.0f + t);
}

__device__ __forceinline__ float2 cmul(float2 a, float2 b) {
    return make_float2(a.x * b.x - a.y * b.y, a.x * b.y + a.y * b.x);
}
__device__ __forceinline__ float2 cadd(float2 a, float2 b) {
    return make_float2(a.x + b.x, a.y + b.y);
}
__device__ __forceinline__ float2 csub(float2 a, float2 b) {
    return make_float2(a.x - b.x, a.y - b.y);
}
// multiply by i*sigma (sigma = +-1)
__device__ __forceinline__ float2 cmuli(float2 z, float s) {
    return make_float2(-s * z.y, s * z.x);
}

// ---------------------------------------------------------------------------
// fp32 -> bf16 cast of all 4 weight matrices in ONE launch.
// ---------------------------------------------------------------------------
__global__ __launch_bounds__(256) void cast_all_kernel(
    const float* __restrict__ s0, const float* __restrict__ s1,
    const float* __restrict__ s2, const float* __restrict__ s3,
    bf16_t* __restrict__ d0, bf16_t* __restrict__ d1,
    bf16_t* __restrict__ d2, bf16_t* __restrict__ d3)
{
    const int b = blockIdx.x;
    const float* s; bf16_t* d; int base;
    if (b < 3072)      { s = s0; d = d0; base = b; }
    else if (b < 4096) { s = s1; d = d1; base = b - 3072; }
    else if (b < 6144) { s = s2; d = d2; base = b - 4096; }
    else               { s = s3; d = d3; base = b - 6144; }
    const int i = (base * 256 + threadIdx.x) * 4;
    const float4 v = *(const float4*)(s + i);
    bf16x4 o;
    o[0] = (bf16_t)v.x; o[1] = (bf16_t)v.y; o[2] = (bf16_t)v.z; o[3] = (bf16_t)v.w;
    *(bf16x4*)(d + i) = o;
}

// ---------------------------------------------------------------------------
// RMSNorm -> bf16 output: one block per row of 1024 floats
// ---------------------------------------------------------------------------
__global__ __launch_bounds__(256) void rmsnorm_bf16_kernel(
    const float* __restrict__ in, const float* __restrict__ w,
    bf16_t* __restrict__ out)
{
    const int row = blockIdx.x;
    const float4* ip = (const float4*)(in + (size_t)row * DD);
    float4 v = ip[threadIdx.x];
    float ss = v.x*v.x + v.y*v.y + v.z*v.z + v.w*v.w;
    #pragma unroll
    for (int off = 32; off > 0; off >>= 1) ss += __shfl_down(ss, off, 64);
    __shared__ float sums[4];
    const int wid = threadIdx.x >> 6;
    if ((threadIdx.x & 63) == 0) sums[wid] = ss;
    __syncthreads();
    const float tot = sums[0] + sums[1] + sums[2] + sums[3];
    const float scale = rsqrtf(tot * (1.0f / (float)DD) + 1e-8f);
    const float4 wv = ((const float4*)w)[threadIdx.x];
    bf16x4 o;
    o[0] = (bf16_t)(v.x * scale * wv.x);
    o[1] = (bf16_t)(v.y * scale * wv.y);
    o[2] = (bf16_t)(v.z * scale * wv.z);
    o[3] = (bf16_t)(v.w * scale * wv.w);
    *(bf16x4*)(out + (size_t)row * DD + threadIdx.x * 4) = o;
}

// ---------------------------------------------------------------------------
// bf16 MFMA GEMM, 512-thread / 8-wave (R7-VERIFIED BEST, total 476.2us):
// 128x128 tile, BK=64, waves 2x4, per-wave 64x32, acc 4x2. VGPR 52 ->
// 4 waves/SIMD (occupancy ~39%, MfmaUtil ~32% measured). Double-buffered
// 2-phase schedule: issue next-tile global_load_lds into buf^1 first,
// compute cur tile, ONE __syncthreads() per K-tile. setprio(1) around MFMA.
// LDS chunk swizzle: 16-B chunk (row,q) at pos row*8+(q^(row&7)); staging
// pre-swizzles the GLOBAL source; fragment ds_reads apply the same XOR ->
// 0 bank conflicts measured.
// Session notes: 8-phase 256^2 port failed 2x on this problem (MfmaUtil
// 26%/10%: vmcnt slack < load latency at this occupancy); XCD-chunk swizzle
// inverted L2 locality (default round-robin already partitions W N-slices
// per XCD); LDS-staged epilogue cut RMW fetch but cost > benefit (HBM at
// 17% of peak is not the critical path); twiddle-table FFT and k256-step10
// variants are within the +-10us run-to-run noise band (R7/R8/R9:
// 476.2/478.8/488.1 for equivalent pipelines).
// EPI: 0 = bias, 1 = bias + residual, 2 = bias + tanh-GELU
// BIASROW: bias indexed by output row (for transposed-output GEMMs)
// ---------------------------------------------------------------------------
template<int EPI, bool BF16OUT, bool BIASROW = false>
__global__ __launch_bounds__(512) void gemm_mfma_kernel(
    const bf16_t* __restrict__ A,    // (M,K)
    const bf16_t* __restrict__ W,    // (N,K)
    const float* __restrict__ bias,  // (N) or (M) if BIASROW
    const float* __restrict__ res,   // (M,N) or nullptr
    float* __restrict__ Cf,          // fp32 out (if !BF16OUT)
    bf16_t* __restrict__ Cb,         // bf16 out (if BF16OUT)
    int M, int N, int K)
{
    __shared__ __align__(16) bf16_t As[2][128 * 64];   // 32 KB
    __shared__ __align__(16) bf16_t Ws[2][128 * 64];   // 32 KB
    const int tid  = threadIdx.x;                      // 0..511
    const int bm   = blockIdx.y * 128;
    const int bn   = blockIdx.x * 128;
    const int lane = tid & 63;
    const int wave = tid >> 6;                         // 0..7
    const int wr   = (wave >> 2) * 64;                 // row-group: 0 / 64
    const int wc   = (wave & 3) * 32;                  // col-group: 0/32/64/96

    // staging: 1024 16-B chunks per matrix; 2 chunks per thread.
    // chunk pos p -> row = p>>3, global chunk q = (p&7)^(row&7)
    int srow[2], sqg[2];
    #pragma unroll
    for (int c = 0; c < 2; ++c) {
        const int p = c * 512 + tid;
        srow[c] = p >> 3;
        sqg[c]  = (((p & 7) ^ (srow[c] & 7)) << 3);
    }

    f32x4 acc[4][2] = {};

    const int fr = lane & 15;
    const int fc = (lane >> 4) * 8;

    const int nt = K >> 6;

    #pragma unroll
    for (int c = 0; c < 2; ++c) {
        GLD_LDS16(A + (size_t)(bm + srow[c]) * K + sqg[c],
                  &As[0][c * 4096 + tid * 8]);
        GLD_LDS16(W + (size_t)(bn + srow[c]) * K + sqg[c],
                  &Ws[0][c * 4096 + tid * 8]);
    }
    __syncthreads();

    int cur = 0;
    for (int t = 0; t < nt; ++t) {
        if (t + 1 < nt) {
            const int k0 = (t + 1) << 6;
            #pragma unroll
            for (int c = 0; c < 2; ++c) {
                GLD_LDS16(A + (size_t)(bm + srow[c]) * K + k0 + sqg[c],
                          &As[cur ^ 1][c * 4096 + tid * 8]);
                GLD_LDS16(W + (size_t)(bn + srow[c]) * K + k0 + sqg[c],
                          &Ws[cur ^ 1][c * 4096 + tid * 8]);
            }
        }
        #pragma unroll
        for (int ks = 0; ks < 64; ks += 32) {
            const int q = (ks + fc) >> 3;
            bf16x8 af[4], wf[2];
            #pragma unroll
            for (int i = 0; i < 4; ++i) {
                const int r = wr + i*16 + fr;
                af[i] = *(const bf16x8*)(&As[cur][r * 64 + ((q ^ (r & 7)) << 3)]);
            }
            #pragma unroll
            for (int j = 0; j < 2; ++j) {
                const int r = wc + j*16 + fr;
                wf[j] = *(const bf16x8*)(&Ws[cur][r * 64 + ((q ^ (r & 7)) << 3)]);
            }
            __builtin_amdgcn_s_setprio(1);
            #pragma unroll
            for (int i = 0; i < 4; ++i)
                #pragma unroll
                for (int j = 0; j < 2; ++j)
                    acc[i][j] = __builtin_amdgcn_mfma_f32_16x16x32_bf16(
                        af[i], wf[j], acc[i][j], 0, 0, 0);
            __builtin_amdgcn_s_setprio(0);
        }
        __syncthreads();
        cur ^= 1;
    }

    // Epilogue. C/D layout: col = lane&15, row = (lane>>4)*4 + reg
    const int fq = lane >> 4;
    #pragma unroll
    for (int i = 0; i < 4; ++i) {
        const int row0 = bm + wr + i*16 + fq*4;
        #pragma unroll
        for (int j = 0; j < 2; ++j) {
            const int col = bn + wc + j*16 + fr;
            const float bcol = BIASROW ? 0.0f : bias[col];
            #pragma unroll
            for (int r = 0; r < 4; ++r) {
                float v = acc[i][j][r] + (BIASROW ? bias[row0 + r] : bcol);
                if constexpr (EPI == 2) v = gelu_tanh(v);
                if constexpr (EPI == 1) v += res[(size_t)(row0 + r) * N + col];
                if constexpr (BF16OUT)
                    Cb[(size_t)(row0 + r) * N + col] = (bf16_t)v;
                else
                    Cf[(size_t)(row0 + r) * N + col] = v;
            }
        }
    }
}

// ---------------------------------------------------------------------------
// Depthwise causal k=3 short filter on u_t (3D, M) channel-major bf16.
// Vectorized bf16x8 loads (16 B/lane), 8 positions per thread, 16-B stores.
// ---------------------------------------------------------------------------
__global__ __launch_bounds__(256) void shortfilter_kernel(
    const bf16_t* __restrict__ ut, const float* __restrict__ sw,
    const float* __restrict__ sb, bf16_t* __restrict__ x0t,
    float* __restrict__ vin)
{
    const int d = blockIdx.x;             // 0..1023
    const int c0 = d, c1 = DD + d, c2 = 2 * DD + d;
    const float w0a = sw[c0*3+0], w0b = sw[c0*3+1], w0c = sw[c0*3+2], b0 = sb[c0];
    const float w1a = sw[c1*3+0], w1b = sw[c1*3+1], w1c = sw[c1*3+2], b1 = sb[c1];
    const float w2a = sw[c2*3+0], w2b = sw[c2*3+1], w2c = sw[c2*3+2], b2 = sb[c2];
    const bf16_t* r0 = ut + (size_t)c0 * MM;
    const bf16_t* r1 = ut + (size_t)c1 * MM;
    const bf16_t* r2 = ut + (size_t)c2 * MM;
    bf16_t* o0 = x0t + (size_t)d * MM;
    float*  o1 = vin + (size_t)d * MM;
    for (int m0 = threadIdx.x * 8; m0 < MM; m0 += 2048) {
        const int l0 = m0 & (LL - 1);
        const bf16x8 a0 = *(const bf16x8*)(r0 + m0);
        const bf16x8 a1 = *(const bf16x8*)(r1 + m0);
        const bf16x8 a2 = *(const bf16x8*)(r2 + m0);
        float u0[10], u1[10], u2[10];
        u0[0] = u0[1] = u1[0] = u1[1] = u2[0] = u2[1] = 0.0f;
        if (l0 != 0) {
            u0[0] = (float)r0[m0-2]; u0[1] = (float)r0[m0-1];
            u1[0] = (float)r1[m0-2]; u1[1] = (float)r1[m0-1];
            u2[0] = (float)r2[m0-2]; u2[1] = (float)r2[m0-1];
        }
        #pragma unroll
        for (int i = 0; i < 8; ++i) {
            u0[i+2] = (float)a0[i];
            u1[i+2] = (float)a1[i];
            u2[i+2] = (float)a2[i];
        }
        bf16x8 ov;
        float v1o[8];
        #pragma unroll
        for (int i = 0; i < 8; ++i) {
            const float v0 = w0c*u0[i+2] + w0b*u0[i+1] + w0a*u0[i] + b0;
            const float v1 = w1c*u1[i+2] + w1b*u1[i+1] + w1a*u1[i] + b1;
            const float v2 = w2c*u2[i+2] + w2b*u2[i+1] + w2a*u2[i] + b2;
            ov[i] = (bf16_t)v0;
            v1o[i] = v2 * v1;
        }
        *(bf16x8*)(o0 + m0) = ov;
        *(float4*)(o1 + m0)     = make_float4(v1o[0], v1o[1], v1o[2], v1o[3]);
        *(float4*)(o1 + m0 + 4) = make_float4(v1o[4], v1o[5], v1o[6], v1o[7]);
    }
}

// ---------------------------------------------------------------------------
// Implicit filter MLP, phase 1: h2t (64, L).
// Block = 32 l-positions x 64 j, grid = 64 blocks.
// ---------------------------------------------------------------------------
__global__ __launch_bounds__(256) void filtermlp_kernel(
    const float* __restrict__ w1, const float* __restrict__ b1,
    const float* __restrict__ f1, const float* __restrict__ w2,
    const float* __restrict__ b2, const float* __restrict__ f2,
    float* __restrict__ h2t)
{
    __shared__ float w2s[64 * 64];      // 16 KB
    __shared__ float h1s[64][32];       // 8 KB, [j][l]
    const int tid = threadIdx.x;
    #pragma unroll
    for (int i = 0; i < 4; ++i)
        ((float4*)w2s)[tid + 256 * i] = ((const float4*)w2)[tid + 256 * i];

    const int l0 = blockIdx.x * 32;
    const int l  = tid & 31;
    const float fl = (float)(l0 + l);
    const float t   = fl * (1.0f / (float)(LL - 1));
    const float ang = 1e-4f * 6.283185307179586f * fl * (1.0f / (float)LL);
    const float z0 = t, z1 = cosf(ang), z2 = -sinf(ang);

    #pragma unroll
    for (int i = 0; i < 8; ++i) {
        const int j = (tid >> 5) + 8 * i;
        const float s = w1[j*3+0]*z0 + w1[j*3+1]*z1 + w1[j*3+2]*z2 + b1[j];
        h1s[j][l] = sinf(f1[j] * s);
    }
    __syncthreads();

    const int jb = (tid >> 5) * 8;
    float acc[8];
    #pragma unroll
    for (int i = 0; i < 8; ++i) acc[i] = b2[jb + i];
    #pragma unroll
    for (int jj = 0; jj < 64; jj += 4) {
        const float h0 = h1s[jj + 0][l];
        const float h1v = h1s[jj + 1][l];
        const float h2v = h1s[jj + 2][l];
        const float h3 = h1s[jj + 3][l];
        #pragma unroll
        for (int i = 0; i < 8; ++i) {
            const float4 wv = *(const float4*)&w2s[(jb + i) * 64 + jj];
            acc[i] += wv.x * h0 + wv.y * h1v + wv.z * h2v + wv.w * h3;
        }
    }
    #pragma unroll
    for (int i = 0; i < 8; ++i)
        h2t[(size_t)(jb + i) * LL + l0 + l] = sinf(f2[jb + i] * acc[i]);
}

// ---------------------------------------------------------------------------
// Implicit filter, phase 2: kfilt[d][l] = (w3[d,:] . h2t[:,l]) * exp(-t|delta_d|)
// ---------------------------------------------------------------------------
__global__ __launch_bounds__(256) void filtermod_kernel(
    const float* __restrict__ w3, const float* __restrict__ h2t,
    float* __restrict__ kfilt)
{
    __shared__ float w3s[32 * 64];      // 8 KB
    const int d0 = blockIdx.y * 32;
    const int l  = blockIdx.x * 256 + threadIdx.x;
    for (int i = threadIdx.x; i < 32 * 64; i += 256) w3s[i] = w3[d0 * 64 + i];
    __syncthreads();
    float acc[32] = {};
    for (int j = 0; j < 64; ++j) {
        const float v = h2t[j * LL + l];
        #pragma unroll
        for (int dd = 0; dd < 32; ++dd) acc[dd] += w3s[dd*64 + j] * v;
    }
    const float t = (float)l / (float)(LL - 1);
    const float min_decay = -3.0701134573253944f;   // ln(1e-2)/1.5
    const float max_decay = -15.350567286626972f;   // ln(1e-2)/0.3
    #pragma unroll
    for (int dd = 0; dd < 32; ++dd) {
        const int d = d0 + dd;
        const float delta = fabsf(min_decay + (max_decay - min_decay) * (float)d / (float)(DD - 1));
        kfilt[(size_t)d * LL + l] = acc[dd] * expf(-t * delta);
    }
}

// ---------------------------------------------------------------------------
// 4096-point complex Stockham RADIX-8 FFT, in-place in 32 KB LDS.
// 4 stages (4096 = 8^4), 512 threads, one 8-point butterfly per thread per
// stage (read-all / barrier / write-all: race-free).
// SIGN = -1 forward, +1 unnormalized inverse. Ends with __syncthreads().
// ---------------------------------------------------------------------------
template<int SIGN>
__device__ __forceinline__ void fft4096_r8_ip(float2* __restrict__ buf)
{
    const float fs = (float)SIGN;
    const float RH = 0.7071067811865476f;   // sqrt(2)/2
    const int tid = threadIdx.x;            // 0..511
    #pragma unroll
    for (int t = 0; t < 4; ++t) {
        const int ls = 3 * t;               // log2(stride): 0,3,6,9
        const int s  = 1 << ls;
        const float theta = fs * 6.283185307179586f / (float)(4096 >> ls);
        float2 a[8];
        #pragma unroll
        for (int m = 0; m < 8; ++m) a[m] = buf[SWZ(tid + m * 512)];
        __syncthreads();
        const int p = tid >> ls;
        const int q = tid & (s - 1);
        float sn, cs;
        __sincosf(theta * (float)p, &sn, &cs);
        const float2 W1 = make_float2(cs, sn);
        const float2 W2 = cmul(W1, W1);
        const float2 W3 = cmul(W2, W1);
        const float2 W4 = cmul(W2, W2);
        const float2 W5 = cmul(W4, W1);
        const float2 W6 = cmul(W4, W2);
        const float2 W7 = cmul(W4, W3);
        // DFT4 of evens (a0,a2,a4,a6) and odds (a1,a3,a5,a7)
        const float2 es = cadd(a[0], a[4]), ed = csub(a[0], a[4]);
        const float2 fs2 = cadd(a[2], a[6]), fd = csub(a[2], a[6]);
        const float2 E0 = cadd(es, fs2);
        const float2 E1 = cadd(ed, cmuli(fd, fs));
        const float2 E2 = csub(es, fs2);
        const float2 E3 = csub(ed, cmuli(fd, fs));
        const float2 os = cadd(a[1], a[5]), od = csub(a[1], a[5]);
        const float2 gs = cadd(a[3], a[7]), gd = csub(a[3], a[7]);
        const float2 O0 = cadd(os, gs);
        const float2 O1 = cadd(od, cmuli(gd, fs));
        const float2 O2 = csub(os, gs);
        const float2 O3 = csub(od, cmuli(gd, fs));
        // T_m = w8^m * O_m  (w8 = e^{i*sign*pi/4})
        const float2 T0 = O0;
        const float2 T1 = make_float2(RH * (O1.x - fs * O1.y), RH * (fs * O1.x + O1.y));
        const float2 T2 = cmuli(O2, fs);
        const float2 T3 = make_float2(RH * (-O3.x - fs * O3.y), RH * (fs * O3.x - O3.y));
        const int o = q + (p << (ls + 3));
        buf[SWZ(o)]         = cadd(E0, T0);
        buf[SWZ(o + s)]     = cmul(W1, cadd(E1, T1));
        buf[SWZ(o + 2*s)]   = cmul(W2, cadd(E2, T2));
        buf[SWZ(o + 3*s)]   = cmul(W3, cadd(E3, T3));
        buf[SWZ(o + 4*s)]   = cmul(W4, csub(E0, T0));
        buf[SWZ(o + 5*s)]   = cmul(W5, csub(E1, T1));
        buf[SWZ(o + 6*s)]   = cmul(W6, csub(E2, T2));
        buf[SWZ(o + 7*s)]   = cmul(W7, csub(E3, T3));
        __syncthreads();
    }
}

// ---------------------------------------------------------------------------
// FFT of filter rows, two real rows per block (z = k_{2d} + i*k_{2d+1}).
// ---------------------------------------------------------------------------
__global__ __launch_bounds__(512, 4) void kfft_kernel(
    const float* __restrict__ kfilt, float2* __restrict__ Kf)
{
    __shared__ float2 fb[4096];           // 32 KB
    const int d0 = blockIdx.x * 2;
    const float* k0 = kfilt + (size_t)d0 * LL;
    const float* k1 = k0 + LL;
    const float inv = 1.0f / 4096.0f;
    const int tid = threadIdx.x;
    for (int i = tid; i < 2048; i += 512) {
        fb[SWZ(i)]        = make_float2(k0[i] * inv, k1[i] * inv);
        fb[SWZ(i + 2048)] = make_float2(0.f, 0.f);
    }
    __syncthreads();
    fft4096_r8_ip<-1>(fb);
    float2* o0 = Kf + (size_t)d0 * KF_STRIDE;
    float2* o1 = o0 + KF_STRIDE;
    for (int k = tid; k <= 2048; k += 512) {
        const float2 z1 = fb[SWZ(k)];
        const float2 z2 = fb[SWZ((4096 - k) & 4095)];
        o0[k] = make_float2(0.5f * (z1.x + z2.x), 0.5f * (z1.y - z2.y));
        o1[k] = make_float2(0.5f * (z1.y + z2.y), 0.5f * (z2.x - z1.x));
    }
}

// ---------------------------------------------------------------------------
// Long conv, two real rows per block: z = v1 + i*v2, filter k is REAL.
// ---------------------------------------------------------------------------
__global__ __launch_bounds__(512, 4) void fftconv_kernel(
    float* __restrict__ vio, const float2* __restrict__ Kf,
    const float* __restrict__ fbias)
{
    __shared__ float2 fb[4096];           // 32 KB
    const int blk = blockIdx.x;          // [0, 2048)
    const int d   = blk >> 1;
    float* v1 = vio + (size_t)(2 * blk) * LL;
    float* v2 = v1 + LL;
    const int tid = threadIdx.x;
    for (int i = tid; i < 2048; i += 512) {
        fb[SWZ(i)]        = make_float2(v1[i], v2[i]);
        fb[SWZ(i + 2048)] = make_float2(0.f, 0.f);
    }
    __syncthreads();
    fft4096_r8_ip<-1>(fb);
    const float2* kf = Kf + (size_t)d * KF_STRIDE;
    for (int i = tid; i < 4096; i += 512) {
        float2 k;
        if (i <= 2048) k = kf[i];
        else { const float2 t = kf[4096 - i]; k = make_float2(t.x, -t.y); }
        fb[SWZ(i)] = cmul(fb[SWZ(i)], k);
    }
    __syncthreads();
    fft4096_r8_ip<1>(fb);
    const float bias = fbias[d];
    for (int i = tid; i < 2048; i += 512) {
        const float2 zy = fb[SWZ(i)];
        v1[i] = zy.x + bias * v1[i];
        v2[i] = zy.y + bias * v2[i];
    }
}

// ---------------------------------------------------------------------------
// gated_bf16(B,L,D) = bf16( y(D,B,L) * x0t(D,B,L) )  -- LDS 32x32 transpose
// ---------------------------------------------------------------------------
__global__ __launch_bounds__(256) void gate_transpose_kernel(
    const float* __restrict__ y, const bf16_t* __restrict__ x0t,
    bf16_t* __restrict__ g)
{
    __shared__ float tile[32][33];
    const int b  = blockIdx.z;
    const int l0 = blockIdx.x * 32;
    const int d0 = blockIdx.y * 32;
    const int tx  = threadIdx.x & 31;
    const int tyb = threadIdx.x >> 5;    // 0..7
    #pragma unroll
    for (int i = 0; i < 4; ++i) {
        const int dy = tyb + i * 8;
        const size_t src = ((size_t)(d0 + dy) * BB + b) * LL + l0 + tx;
        tile[dy][tx] = y[src] * (float)x0t[src];
    }
    __syncthreads();
    #pragma unroll
    for (int i = 0; i < 4; ++i) {
        const int ly = tyb + i * 8;
        g[((size_t)(b * LL + l0 + ly)) * DD + d0 + tx] = (bf16_t)tile[tx][ly];
    }
}

// ---------------------------------------------------------------------------
// Launch
// ---------------------------------------------------------------------------
extern "C" void kernel_launch(void* const* d_in, const int* in_sizes, int n_in,
                              void* d_out, int out_size, void* d_ws, size_t ws_size,
                              hipStream_t stream)
{
    (void)in_sizes; (void)n_in; (void)out_size; (void)ws_size;
    const float* x   = (const float*)d_in[0];
    const float* nw0 = (const float*)d_in[1];
    const float* ipw = (const float*)d_in[2];
    const float* ipb = (const float*)d_in[3];
    const float* sfw = (const float*)d_in[4];
    const float* sfb = (const float*)d_in[5];
    const float* w1  = (const float*)d_in[6];
    const float* b1  = (const float*)d_in[7];
    const float* f1  = (const float*)d_in[8];
    const float* w2  = (const float*)d_in[9];
    const float* b2  = (const float*)d_in[10];
    const float* f2  = (const float*)d_in[11];
    const float* w3  = (const float*)d_in[12];
    const float* fbv = (const float*)d_in[13];
    const float* opw = (const float*)d_in[14];
    const float* opb = (const float*)d_in[15];
    const float* nw1 = (const float*)d_in[16];
    const float* fw1 = (const float*)d_in[17];
    const float* fb1 = (const float*)d_in[18];
    const float* fw2 = (const float*)d_in[19];
    const float* fb2 = (const float*)d_in[20];
    float* out = (float*)d_out;

    float* ws = (float*)d_ws;
    bf16_t* utb    = (bf16_t*)ws;
    bf16_t* gatedb = (bf16_t*)ws;                       // 8,388,608 bf16
    float*  h      = ws + 4194304;                      // 8,388,608 f
    bf16_t* midb   = (bf16_t*)(ws + 12582912);          // 16,777,216 bf16
    bf16_t* xnb    = (bf16_t*)(ws + 25165824);          // 8M bf16 (also hn later)
    bf16_t* x0tb   = (bf16_t*)(ws + 29360128);          // 8,388,608 bf16 (D,B,L)
    float*  vio    = ws + 37748736;                     // 8,388,608 f (D,B,L)
    float*  kfilt  = ws + 46137344;                     // 2,097,152 f
    float2* Kf     = (float2*)(ws + 48234496);          // 1024 x KF_STRIDE cplx
    bf16_t* ipwb   = (bf16_t*)(ws + 52445184);          // 3,145,728 bf16
    bf16_t* opwb   = ipwb + 3145728;                    // 1,048,576 bf16
    bf16_t* fw1b   = opwb + 1048576;                    // 2,097,152 bf16
    bf16_t* fw2b   = fw1b + 2097152;                    // 2,097,152 bf16
    float*  h2t    = ws + 56639488;                     // (64, L) = 131,072 f

    // 0. weight casts (single launch, region-dispatched)
    cast_all_kernel<<<8192, 256, 0, stream>>>(ipw, opw, fw1, fw2,
                                              ipwb, opwb, fw1b, fw2b);
    // 1. implicit filter: MLP phase (h2t), modulation phase (kfilt), FFT (Kf)
    filtermlp_kernel<<<LL/32, 256, 0, stream>>>(w1, b1, f1, w2, b2, f2, h2t);
    filtermod_kernel<<<dim3(LL/256, DD/32), 256, 0, stream>>>(w3, h2t, kfilt);
    kfft_kernel<<<DD/2, 512, 0, stream>>>(kfilt, Kf);
    // 2. xn = bf16(rmsnorm(x, norm_in_w))
    rmsnorm_bf16_kernel<<<MM, 256, 0, stream>>>(x, nw0, xnb);
    // 3. u_t = in_proj_w @ xn^T + b (transposed output, bf16)
    gemm_mfma_kernel<0, true, true><<<dim3(MM/128, 3072/128), 512, 0, stream>>>(
        ipwb, xnb, ipb, nullptr, nullptr, utb, 3*DD, MM, DD);
    // 4. short filter -> x0t (D,B,L) bf16, vin (D,B,L) fp32
    shortfilter_kernel<<<DD, 256, 0, stream>>>(utb, sfw, sfb, x0tb, vio);
    // 5. vio <- causal_conv(vio, k) + filter_bias * vio   (2 rows per block)
    fftconv_kernel<<<BB*DD/2, 512, 0, stream>>>(vio, Kf, fbv);
    // 6. gated_bf16(B,L,D) = y * x0
    gate_transpose_kernel<<<dim3(LL/32, DD/32, BB), 256, 0, stream>>>(vio, x0tb, gatedb);
    // 7. h = gated @ out_proj_w^T + b + x   (M=8192, N=1024, K=1024)
    gemm_mfma_kernel<1, false><<<dim3(DD/128, MM/128), 512, 0, stream>>>(
        gatedb, opwb, opb, x, h, nullptr, MM, DD, DD);
    // 8. hn = bf16(rmsnorm(h, norm_w))
    rmsnorm_bf16_kernel<<<MM, 256, 0, stream>>>(h, nw1, xnb);
    // 9. mid = bf16(gelu(hn @ ffn_w1^T + b))  (M=8192, N=2048, K=1024)
    gemm_mfma_kernel<2, true><<<dim3(2*DD/128, MM/128), 512, 0, stream>>>(
        xnb, fw1b, fb1, nullptr, nullptr, midb, MM, 2*DD, DD);
    // 10. out = mid @ ffn_w2^T + b + h      (M=8192, N=1024, K=2048)
    gemm_mfma_kernel<1, false><<<dim3(DD/128, MM/128), 512, 0, stream>>>(
        midb, fw2b, fb2, h, out, nullptr, MM, DD, 2*DD);
}